// Round 10
// baseline (913.312 us; speedup 1.0000x reference)
//
#include <hip/hip_runtime.h>
#include <hip/hip_fp16.h>
#include <hip/hip_cooperative_groups.h>

namespace cg = cooperative_groups;

#define N_NODES 50000
#define N_EDGES 800000
#define NUM_GRAPHS 256
#define D 64
#define EPS 1e-5f
#define N_PART 8
#define PART_SIZE (N_NODES / N_PART)   // 6250
#define SCAT_CHUNKS 512
#define SCAT_GRID (SCAT_CHUNKS * N_PART)     // 4096
#define GEMM_BLOCKS ((N_NODES + 63) / 64)    // 782
#define WP 72        // padded LDS row stride in halves
#define MEGA_GRID 1024                       // 4 blocks/CU x 256 CUs (guaranteed)

typedef _Float16 half8_t __attribute__((ext_vector_type(8)));
typedef _Float16 half4_t __attribute__((ext_vector_type(4)));
typedef float f32x4 __attribute__((ext_vector_type(4)));

struct GParams {
    const int* ei; const float* x; const int* batch;
    const float *W0,*b0,*g0,*bb0,*m0,*v0;
    const float *W1,*b1,*g1,*bb1,*m1,*v1;
    const float *hW1,*hb1,*hg1,*hbb1,*hm1,*hv1;
    const float *hW2,*hb2,*hg2,*hbb2,*hm2,*hv2;
    const float *hW3,*hb3,*hW4,*hb4;
    __half* xwhA;   // N*64 fp16: table0, then reused for table1
    __half* xwhB;   // N*64 fp16: h0
    float*  bufB;   // N*64 f32:  h1
    int* cnt; unsigned short* ssrc;
    float* out; int cap;
};

// ---------------------------------------------------------------------------
__device__ __forceinline__ void acc16(const uint4& v, float w, float4& A, float4& B) {
    const __half2* hp = (const __half2*)&v;
    float2 q0 = __half22float2(hp[0]), q1 = __half22float2(hp[1]);
    float2 q2 = __half22float2(hp[2]), q3 = __half22float2(hp[3]);
    A.x += w * q0.x; A.y += w * q0.y; A.z += w * q1.x; A.w += w * q1.y;
    B.x += w * q2.x; B.y += w * q2.y; B.z += w * q3.x; B.w += w * q3.y;
}

// ---------------------------------------------------------------------------
// XCD-partitioned slotted-CSR scatter chunk (round-4 proven: partitioning keeps
// each dst-range's cnt/ssrc lines on ONE XCD's L2 -> single writeback/line).
__device__ __forceinline__ void scatter_chunk_dev(const GParams& P, int su) {
    int p     = su & (N_PART - 1);
    int chunk = su >> 3;
    const int per = (((N_EDGES + SCAT_CHUNKS - 1) / SCAT_CHUNKS) + 3) & ~3;  // 1564
    int lo = chunk * per;
    int hi = lo + per; if (hi > N_EDGES) hi = N_EDGES;
    for (int e4 = lo + (int)threadIdx.x * 4; e4 < hi; e4 += 1024) {
        int4 c4 = *(const int4*)&P.ei[N_EDGES + e4];   // 16B-aligned (lo%4==0)
        const int* cc = (const int*)&c4;
#pragma unroll
        for (int k = 0; k < 4; k++) {
            int e = e4 + k;
            if (e < hi) {
                int c = cc[k];
                if (c / PART_SIZE == p) {
                    int r = P.ei[e];
                    int pos = atomicAdd(&P.cnt[c], 1);
                    if (pos < P.cap) P.ssrc[(size_t)c * P.cap + pos] = (unsigned short)r;
                }
            }
        }
    }
}

// ---------------------------------------------------------------------------
// gemm0 tile: table0[base..base+63] = fp16(X @ W0), unscaled. NT loads of X
// (read-once); PLAIN stores (round-8/9 lesson: tables must stay cache-resident).
__device__ __forceinline__ void gemm_tile_f32in(const GParams& P, int base,
                                                _Float16* Xs, _Float16* Wt) {
    int tid = threadIdx.x;
    for (int i = tid; i < 4096; i += 256) {       // stage W0^T fp16
        int k = i >> 6, n = i & 63;
        Wt[n * WP + k] = (_Float16)P.W0[i];
    }
    for (int i = tid; i < 1024; i += 256) {       // stage X rows fp16 (NT)
        int r = i >> 4, c4 = (i & 15) * 4;
        f32x4 xv;
        if (base + r < N_NODES) {
            xv = __builtin_nontemporal_load(
                     &((const f32x4*)P.x)[(size_t)(base + r) * 16 + (i & 15)]);
        } else {
            xv = (f32x4){0.f, 0.f, 0.f, 0.f};
        }
        _Float16* dst = &Xs[r * WP + c4];
        dst[0] = (_Float16)xv.x; dst[1] = (_Float16)xv.y;
        dst[2] = (_Float16)xv.z; dst[3] = (_Float16)xv.w;
    }
    __syncthreads();
    int wave = tid >> 6, lane = tid & 63;
    int m = lane & 15, q = lane >> 4;
    int row16 = wave * 16;
    half8_t a0 = *(const half8_t*)&Xs[(row16 + m) * WP + q * 8];
    half8_t a1 = *(const half8_t*)&Xs[(row16 + m) * WP + 32 + q * 8];
#pragma unroll
    for (int ct = 0; ct < 4; ct++) {
        half8_t b0 = *(const half8_t*)&Wt[(ct * 16 + m) * WP + q * 8];
        half8_t b1 = *(const half8_t*)&Wt[(ct * 16 + m) * WP + 32 + q * 8];
        f32x4 c = {0.f, 0.f, 0.f, 0.f};
        c = __builtin_amdgcn_mfma_f32_16x16x32_f16(a0, b0, c, 0, 0, 0);
        c = __builtin_amdgcn_mfma_f32_16x16x32_f16(a1, b1, c, 0, 0, 0);
#pragma unroll
        for (int reg = 0; reg < 4; reg++) {
            int row = base + row16 + q * 4 + reg;
            if (row < N_NODES)
                P.xwhA[(size_t)row * 64 + ct * 16 + m] = (__half)c[reg];
        }
    }
    __syncthreads();   // protect LDS for any reuse
}

// gemm1 tile: table1[base..] = fp16(h0 @ W1), unscaled, plain store.
__device__ __forceinline__ void gemm_tile_f16in(const GParams& P, int base,
                                                _Float16* Xs, _Float16* Wt) {
    int tid = threadIdx.x;
    for (int i = tid; i < 4096; i += 256) {
        int k = i >> 6, n = i & 63;
        Wt[n * WP + k] = (_Float16)P.W1[i];
    }
    for (int i = tid; i < 512; i += 256) {   // 64 rows x 8 16B-chunks
        int r = i >> 3, c8 = (i & 7) * 8;
        uint4 v = (base + r < N_NODES)
            ? ((const uint4*)P.xwhB)[(size_t)(base + r) * 8 + (i & 7)]
            : make_uint4(0u, 0u, 0u, 0u);
        *(uint4*)&Xs[r * WP + c8] = v;
    }
    __syncthreads();
    int wave = tid >> 6, lane = tid & 63;
    int m = lane & 15, q = lane >> 4;
    int row16 = wave * 16;
    half8_t a0 = *(const half8_t*)&Xs[(row16 + m) * WP + q * 8];
    half8_t a1 = *(const half8_t*)&Xs[(row16 + m) * WP + 32 + q * 8];
#pragma unroll
    for (int ct = 0; ct < 4; ct++) {
        half8_t b0 = *(const half8_t*)&Wt[(ct * 16 + m) * WP + q * 8];
        half8_t b1 = *(const half8_t*)&Wt[(ct * 16 + m) * WP + 32 + q * 8];
        f32x4 c = {0.f, 0.f, 0.f, 0.f};
        c = __builtin_amdgcn_mfma_f32_16x16x32_f16(a0, b0, c, 0, 0, 0);
        c = __builtin_amdgcn_mfma_f32_16x16x32_f16(a1, b1, c, 0, 0, 0);
#pragma unroll
        for (int reg = 0; reg < 4; reg++) {
            int row = base + row16 + q * 4 + reg;
            if (row < N_NODES)
                P.xwhA[(size_t)row * 64 + ct * 16 + m] = (__half)c[reg];
        }
    }
    __syncthreads();
}

// ---------------------------------------------------------------------------
// wave-per-node aggregation + self-loop + gcn bias + BN + ReLU (round-4 body).
// MODE 0: layer 0 (BN set 0), writes h0 fp16 to xwhB.
// MODE 1: layer 1 (BN set 1), writes h1 f32 to bufB.
template<int MODE>
__device__ __forceinline__ void agg_node_dev(const GParams& P, int c, int lane) {
    const float* b   = MODE ? P.b1  : P.b0;
    const float* g   = MODE ? P.g1  : P.g0;
    const float* bb  = MODE ? P.bb1 : P.bb0;
    const float* m   = MODE ? P.m1  : P.m0;
    const float* var = MODE ? P.v1  : P.v0;
    int cap = P.cap;
    int sub = lane >> 3;        // which of 8 concurrent edges
    int f2  = lane & 7;         // feature group
    const uint4* xw8 = (const uint4*)P.xwhA;
    int n = P.cnt[c];
    if (n > cap) n = cap;
    float dc = rsqrtf((float)n + 1.0f);
    size_t sbase = (size_t)c * cap;
    int idx = (lane < cap) ? (int)P.ssrc[sbase + lane] : 0;
    uint4 vself = make_uint4(0u, 0u, 0u, 0u);
    if (sub == 0) vself = xw8[(size_t)c * 8 + f2];
    int t = (n + 7) >> 3;
    float4 accA = make_float4(0.f, 0.f, 0.f, 0.f);
    float4 accB = accA;
    uint4 v0 = make_uint4(0u,0u,0u,0u), v1 = v0;
    int   cv0 = -1, cv1 = -1;
    auto issue = [&](int k, uint4& v, int& cv) {
        int s = k * 8 + sub;
        int sc = (s < n) ? s : 0;            // shfl executed by ALL lanes
        int r  = __shfl(idx, sc, 64);
        if (s >= n) r = c;                   // redirect invalid to cache-hot row
        cv = (s < n) ? P.cnt[r] : -1;        // cnt gather ∥ row gather
        v  = xw8[(size_t)r * 8 + f2];
    };
    auto consume = [&](const uint4& v, int cv) {
        if (cv >= 0) acc16(v, rsqrtf((float)cv + 1.0f), accA, accB);
    };
    if (t > 0) issue(0, v0, cv0);
    if (t > 1) issue(1, v1, cv1);
    for (int k = 0; k < t; k++) {
        consume(v0, cv0);
        v0 = v1; cv0 = cv1;
        if (k + 2 < t) issue(k + 2, v1, cv1); else cv1 = -1;
    }
    if (sub == 0) acc16(vself, dc, accA, accB);
#pragma unroll
    for (int off = 8; off < 64; off <<= 1) {
        accA.x += __shfl_xor(accA.x, off, 64); accA.y += __shfl_xor(accA.y, off, 64);
        accA.z += __shfl_xor(accA.z, off, 64); accA.w += __shfl_xor(accA.w, off, 64);
        accB.x += __shfl_xor(accB.x, off, 64); accB.y += __shfl_xor(accB.y, off, 64);
        accB.z += __shfl_xor(accB.z, off, 64); accB.w += __shfl_xor(accB.w, off, 64);
    }
    if (sub < 2) {
        int i4 = 2 * f2 + sub;
        float4 acc = sub ? accB : accA;
        float4 b4  = ((const float4*)b)[i4];
        float4 m4  = ((const float4*)m)[i4];
        float4 v4_ = ((const float4*)var)[i4];
        float4 g4  = ((const float4*)g)[i4];
        float4 bb4 = ((const float4*)bb)[i4];
        float4 h;
        h.x = (acc.x * dc + b4.x - m4.x) * (1.0f / sqrtf(v4_.x + EPS)) * g4.x + bb4.x;
        h.y = (acc.y * dc + b4.y - m4.y) * (1.0f / sqrtf(v4_.y + EPS)) * g4.y + bb4.y;
        h.z = (acc.z * dc + b4.z - m4.z) * (1.0f / sqrtf(v4_.z + EPS)) * g4.z + bb4.z;
        h.w = (acc.w * dc + b4.w - m4.w) * (1.0f / sqrtf(v4_.w + EPS)) * g4.w + bb4.w;
        h.x = h.x > 0.f ? h.x : 0.f;
        h.y = h.y > 0.f ? h.y : 0.f;
        h.z = h.z > 0.f ? h.z : 0.f;
        h.w = h.w > 0.f ? h.w : 0.f;
        if (MODE == 0) {
            half4_t hv = {(_Float16)h.x, (_Float16)h.y, (_Float16)h.z, (_Float16)h.w};
            *(half4_t*)(P.xwhB + (size_t)c * 64 + i4 * 4) = hv;
        } else {
            ((float4*)P.bufB)[(size_t)c * 16 + i4] = h;
        }
    }
}

// ---------------------------------------------------------------------------
// mean-pool (sorted-batch binary search) + MLP head for graph g (round-4 body).
// smem: carved scratch (>= 770 floats).
__device__ __forceinline__ void pool_head_dev(const GParams& P, int g, float* smem) {
    float* red    = smem;          // 256
    float* pooled = red + 256;     // 64
    float* z1     = pooled + 64;   // 256
    float* z2     = z1 + 256;      // 128
    float* z3     = z2 + 128;      // 64
    int*   se     = (int*)(z3 + 64); // 2
    int t = threadIdx.x;
    if (t < 2) {
        int target = g + t;
        int lo = 0, hi = N_NODES;
        while (lo < hi) {
            int mid = (lo + hi) >> 1;
            if (P.batch[mid] < target) lo = mid + 1; else hi = mid;
        }
        se[t] = lo;
    }
    __syncthreads();
    int start = se[0], end = se[1];
    {
        int f = t & 63, rg = t >> 6;
        float part = 0.0f;
        for (int r = start + rg; r < end; r += 4) part += P.bufB[(size_t)r * 64 + f];
        red[t] = part;
        __syncthreads();
        if (t < 64) {
            float s = red[t] + red[t + 64] + red[t + 128] + red[t + 192];
            float cnt = (float)(end - start);
            cnt = cnt > 1.0f ? cnt : 1.0f;
            pooled[t] = s / cnt;
        }
    }
    __syncthreads();
    {   // layer 1: 64 -> 256, BN + relu
        float acc = P.hb1[t];
#pragma unroll
        for (int k = 0; k < 64; k++) acc += pooled[k] * P.hW1[k * 256 + t];
        acc = (acc - P.hm1[t]) * (1.0f / sqrtf(P.hv1[t] + EPS)) * P.hg1[t] + P.hbb1[t];
        z1[t] = acc > 0.0f ? acc : 0.0f;
    }
    __syncthreads();
    if (t < 128) {  // layer 2: 256 -> 128
        float acc = P.hb2[t];
#pragma unroll 8
        for (int k = 0; k < 256; k++) acc += z1[k] * P.hW2[k * 128 + t];
        acc = (acc - P.hm2[t]) * (1.0f / sqrtf(P.hv2[t] + EPS)) * P.hg2[t] + P.hbb2[t];
        z2[t] = acc > 0.0f ? acc : 0.0f;
    }
    __syncthreads();
    if (t < 64) {   // layer 3: 128 -> 64
        float acc = P.hb3[t];
#pragma unroll 8
        for (int k = 0; k < 128; k++) acc += z2[k] * P.hW3[k * 64 + t];
        z3[t] = acc > 0.0f ? acc : 0.0f;
    }
    __syncthreads();
    if (t < 64) {   // layer 4: 64 -> 1
        float v = z3[t] * P.hW4[t];
        for (int off = 32; off > 0; off >>= 1) v += __shfl_down(v, off, 64);
        if (t == 0) P.out[g] = v + P.hb4[0];
    }
}

// ---------------------------------------------------------------------------
// MEGAKERNEL: all 6 phases, one launch, grid.sync between dependent phases.
// 1024 blocks x 256 thr; __launch_bounds__(256,4) guarantees 4 blocks/CU
// co-residency (VGPR<=128, LDS 18.4KB*4=74KB<=160KB).
__global__ __launch_bounds__(256, 4) void mega_kernel(GParams P) {
    __shared__ _Float16 Xs[64 * WP];
    __shared__ _Float16 Wt[64 * WP];
    cg::grid_group grid = cg::this_grid();
    int tid = threadIdx.x, bid = blockIdx.x;
    // P0: zero cnt (replaces hipMemsetAsync)
    for (int i = bid * 256 + tid; i < N_NODES; i += MEGA_GRID * 256) P.cnt[i] = 0;
    grid.sync();
    // P1: gemm0 tiles (units 0..781) + partitioned scatter (units 782..4877).
    // Block b's scatter units all share partition (b+2)&7 -> stable XCD affinity.
    for (int u = bid; u < GEMM_BLOCKS + SCAT_GRID; u += MEGA_GRID) {
        if (u < GEMM_BLOCKS) gemm_tile_f32in(P, u * 64, Xs, Wt);
        else                 scatter_chunk_dev(P, u - GEMM_BLOCKS);
    }
    grid.sync();
    // P2: agg0 + BN + ReLU -> h0 fp16 (wave-per-node)
    {
        int wave = tid >> 6, lane = tid & 63;
        for (int c = bid * 4 + wave; c < N_NODES; c += MEGA_GRID * 4)
            agg_node_dev<0>(P, c, lane);
    }
    grid.sync();
    // P3: gemm1 -> table1 (one tile per block, blocks 0..781)
    for (int u = bid; u < GEMM_BLOCKS; u += MEGA_GRID)
        gemm_tile_f16in(P, u * 64, Xs, Wt);
    grid.sync();
    // P4: agg1 + BN + ReLU -> h1 f32
    {
        int wave = tid >> 6, lane = tid & 63;
        for (int c = bid * 4 + wave; c < N_NODES; c += MEGA_GRID * 4)
            agg_node_dev<1>(P, c, lane);
    }
    grid.sync();
    // P5: mean pool + MLP head (blocks 0..255)
    if (bid < NUM_GRAPHS) pool_head_dev(P, bid, (float*)Xs);
}

// ---------------------------------------------------------------------------
// Fallback path (round-4 structure) if cooperative launch is unavailable.
__global__ __launch_bounds__(256) void fb_build_gemm(GParams P) {
    __shared__ _Float16 Xs[64 * WP];
    __shared__ _Float16 Wt[64 * WP];
    if (blockIdx.x >= GEMM_BLOCKS) scatter_chunk_dev(P, blockIdx.x - GEMM_BLOCKS);
    else                           gemm_tile_f32in(P, blockIdx.x * 64, Xs, Wt);
}
template<int MODE>
__global__ __launch_bounds__(256) void fb_agg(GParams P) {
    int wave = (blockIdx.x * 256 + threadIdx.x) >> 6;
    if (wave < N_NODES) agg_node_dev<MODE>(P, wave, threadIdx.x & 63);
}
__global__ __launch_bounds__(256) void fb_gemm1(GParams P) {
    __shared__ _Float16 Xs[64 * WP];
    __shared__ _Float16 Wt[64 * WP];
    gemm_tile_f16in(P, blockIdx.x * 64, Xs, Wt);
}
__global__ __launch_bounds__(256) void fb_pool_head(GParams P) {
    __shared__ float lds[772];
    pool_head_dev(P, blockIdx.x, lds);
}

// ---------------------------------------------------------------------------
extern "C" void kernel_launch(void* const* d_in, const int* in_sizes, int n_in,
                              void* d_out, int out_size, void* d_ws, size_t ws_size,
                              hipStream_t stream) {
    GParams P;
    P.ei    = (const int*)d_in[1];
    P.x     = (const float*)d_in[0];
    P.batch = (const int*)d_in[2];
    P.W0 = (const float*)d_in[3];  P.b0 = (const float*)d_in[4];
    P.g0 = (const float*)d_in[5];  P.bb0 = (const float*)d_in[6];
    P.m0 = (const float*)d_in[7];  P.v0 = (const float*)d_in[8];
    P.W1 = (const float*)d_in[9];  P.b1 = (const float*)d_in[10];
    P.g1 = (const float*)d_in[11]; P.bb1 = (const float*)d_in[12];
    P.m1 = (const float*)d_in[13]; P.v1 = (const float*)d_in[14];
    P.hW1 = (const float*)d_in[15]; P.hb1 = (const float*)d_in[16];
    P.hg1 = (const float*)d_in[17]; P.hbb1 = (const float*)d_in[18];
    P.hm1 = (const float*)d_in[19]; P.hv1 = (const float*)d_in[20];
    P.hW2 = (const float*)d_in[21]; P.hb2 = (const float*)d_in[22];
    P.hg2 = (const float*)d_in[23]; P.hbb2 = (const float*)d_in[24];
    P.hm2 = (const float*)d_in[25]; P.hv2 = (const float*)d_in[26];
    P.hW3 = (const float*)d_in[27]; P.hb3 = (const float*)d_in[28];
    P.hW4 = (const float*)d_in[29]; P.hb4 = (const float*)d_in[30];
    P.out = (float*)d_out;

    // workspace layout (round-4): tables, h0, h1, cnt, ssrc
    P.xwhA = (__half*)d_ws;                               // N*64 fp16
    P.xwhB = P.xwhA + (size_t)N_NODES * D;                // N*64 fp16
    P.bufB = (float*)(P.xwhB + (size_t)N_NODES * D);      // N*64 f32
    P.cnt  = (int*)(P.bufB + (size_t)N_NODES * D);        // N ints
    P.ssrc = (unsigned short*)(P.cnt + N_NODES);          // N*cap ushorts

    size_t used = (size_t)2 * N_NODES * D * 2 + (size_t)N_NODES * D * 4
                + (size_t)N_NODES * 4;
    int cap = 64;
    if (ws_size >= used) {
        size_t avail = (ws_size - used) / ((size_t)N_NODES * 2);
        if (avail < (size_t)cap) cap = (int)avail & ~7;
    } else {
        cap = 0;
    }
    P.cap = cap;

    // single cooperative launch: all phases, 5 grid syncs, zero launch gaps
    void* kargs[] = { &P };
    hipError_t err = hipLaunchCooperativeKernel((const void*)mega_kernel,
                                                dim3(MEGA_GRID), dim3(256),
                                                kargs, 0, stream);
    if (err != hipSuccess) {
        (void)hipGetLastError();   // clear sticky error, use classic path
        (void)hipMemsetAsync(P.cnt, 0, (size_t)N_NODES * 4, stream);
        fb_build_gemm<<<SCAT_GRID + GEMM_BLOCKS, 256, 0, stream>>>(P);
        fb_agg<0><<<(N_NODES * 64) / 256, 256, 0, stream>>>(P);
        fb_gemm1<<<GEMM_BLOCKS, 256, 0, stream>>>(P);
        fb_agg<1><<<(N_NODES * 64) / 256, 256, 0, stream>>>(P);
        fb_pool_head<<<NUM_GRAPHS, 256, 0, stream>>>(P);
    }
}

// Round 11
// 265.415 us; speedup vs baseline: 3.4411x; 3.4411x over previous
//
#include <hip/hip_runtime.h>
#include <hip/hip_bf16.h>
#include <hip/hip_fp16.h>

#define N_NODES 50000
#define N_EDGES 800000
#define NUM_GRAPHS 256
#define D 64
#define EPS 1e-5f
#define N_PART 8
#define PART_SIZE (N_NODES / N_PART)   // 6250
#define SCAT_CHUNKS 512
#define SCAT_GRID (SCAT_CHUNKS * N_PART)
#define GEMM_BLOCKS ((N_NODES + 63) / 64)   // 782
#define WP 72   // padded LDS row stride in halves (16B-aligned, conflict-breaking)

typedef _Float16 half8_t __attribute__((ext_vector_type(8)));
typedef _Float16 half4_t __attribute__((ext_vector_type(4)));
typedef float f32x4 __attribute__((ext_vector_type(4)));

// ---------------------------------------------------------------------------
// accumulate a 16B (8-half) chunk with weight w into two float4 accumulators
__device__ __forceinline__ void acc16(const uint4& v, float w, float4& A, float4& B) {
    const __half2* hp = (const __half2*)&v;
    float2 q0 = __half22float2(hp[0]), q1 = __half22float2(hp[1]);
    float2 q2 = __half22float2(hp[2]), q3 = __half22float2(hp[3]);
    A.x += w * q0.x; A.y += w * q0.y; A.z += w * q1.x; A.w += w * q1.y;
    B.x += w * q2.x; B.y += w * q2.y; B.z += w * q3.x; B.w += w * q3.y;
}

// ---------------------------------------------------------------------------
// 1) FUSED: gemm0 (blocks 0..781) ∥ XCD-partitioned slotted-CSR build
//    (blocks 782..).  Scatter now LDS-COMPACTS matching edges first (scan
//    phase: ~1/8 lanes active), then flushes the queue with ALL 64 lanes
//    active per atomic instruction — ~8x fewer atomic wave-instructions.
//    Queue aliases the gemm's Xs LDS (scatter blocks never run gemm).
//    Table is UNSCALED fp16 — dinv applied per-edge in agg (no cnt dep).
__global__ __launch_bounds__(256) void build_gemm_kernel(
        const int* __restrict__ ei, int* __restrict__ cnt,
        unsigned short* __restrict__ ssrc, int cap,
        const float* __restrict__ X, const float* __restrict__ W,
        __half* __restrict__ Yh) {
    __shared__ _Float16 Xs[64 * WP];   // [row][k]  (scatter: aliased as queue)
    __shared__ _Float16 Wt[64 * WP];   // [n][k]
    __shared__ int qn;
    if (blockIdx.x >= GEMM_BLOCKS) {
        // ---- scatter part (blockIdx&7 -> XCD affinity on dst partition) ----
        int scat  = blockIdx.x - GEMM_BLOCKS;
        int p     = blockIdx.x & (N_PART - 1);
        int chunk = scat >> 3;
        const int per = (((N_EDGES + SCAT_CHUNKS - 1) / SCAT_CHUNKS) + 3) & ~3;  // 1564
        int lo = chunk * per;
        int hi = lo + per; if (hi > N_EDGES) hi = N_EDGES;
        unsigned* q = (unsigned*)Xs;          // 2304 slots >= per (1564)
        if (threadIdx.x == 0) qn = 0;
        __syncthreads();
        // scan phase: compact matching edges into LDS queue
        for (int e4 = lo + (int)threadIdx.x * 4; e4 < hi; e4 += 1024) {
            int4 c4 = *(const int4*)&ei[N_EDGES + e4];   // 16B-aligned: lo%4==0
            const int* cc = (const int*)&c4;
#pragma unroll
            for (int k = 0; k < 4; k++) {
                int e = e4 + k;
                if (e < hi) {
                    int c = cc[k];
                    if (c / PART_SIZE == p) {
                        int r = ei[e];                    // r,c < 65536: pack
                        int s = atomicAdd(&qn, 1);
                        q[s] = ((unsigned)c << 16) | (unsigned)r;
                    }
                }
            }
        }
        __syncthreads();
        // flush phase: full-lane atomic + store
        int nq = qn;
        for (int i = (int)threadIdx.x; i < nq; i += 256) {
            unsigned pk = q[i];
            int c = (int)(pk >> 16);
            int r = (int)(pk & 0xffffu);
            int pos = atomicAdd(&cnt[c], 1);
            if (pos < cap) ssrc[(size_t)c * cap + pos] = (unsigned short)r;
        }
        return;
    }
    // ---- gemm0 part ----
    int tid  = threadIdx.x;
    int base = blockIdx.x * 64;
    for (int i = tid; i < 4096; i += 256) {       // stage W^T fp16
        int k = i >> 6, n = i & 63;
        Wt[n * WP + k] = (_Float16)W[i];
    }
    for (int i = tid; i < 1024; i += 256) {       // stage X rows fp16 (NT loads)
        int r = i >> 4, c4 = (i & 15) * 4;
        f32x4 xv;
        if (base + r < N_NODES) {
            xv = __builtin_nontemporal_load(
                     &((const f32x4*)X)[(size_t)(base + r) * 16 + (i & 15)]);
        } else {
            xv = (f32x4){0.f, 0.f, 0.f, 0.f};
        }
        _Float16* dst = &Xs[r * WP + c4];
        dst[0] = (_Float16)xv.x; dst[1] = (_Float16)xv.y;
        dst[2] = (_Float16)xv.z; dst[3] = (_Float16)xv.w;
    }
    __syncthreads();
    int wave  = tid >> 6;
    int lane  = tid & 63;
    int m     = lane & 15;
    int q_    = lane >> 4;
    int row16 = wave * 16;
    half8_t a0 = *(const half8_t*)&Xs[(row16 + m) * WP + q_ * 8];
    half8_t a1 = *(const half8_t*)&Xs[(row16 + m) * WP + 32 + q_ * 8];
    f32x4 acc[4];
#pragma unroll
    for (int ct = 0; ct < 4; ct++) {
        half8_t b0 = *(const half8_t*)&Wt[(ct * 16 + m) * WP + q_ * 8];
        half8_t b1 = *(const half8_t*)&Wt[(ct * 16 + m) * WP + 32 + q_ * 8];
        f32x4 c = {0.f, 0.f, 0.f, 0.f};
        c = __builtin_amdgcn_mfma_f32_16x16x32_f16(a0, b0, c, 0, 0, 0);
        c = __builtin_amdgcn_mfma_f32_16x16x32_f16(a1, b1, c, 0, 0, 0);
        acc[ct] = c;
    }
#pragma unroll
    for (int ct = 0; ct < 4; ct++) {
#pragma unroll
        for (int reg = 0; reg < 4; reg++) {
            int row = base + row16 + q_ * 4 + reg;
            if (row < N_NODES)
                Yh[(size_t)row * 64 + ct * 16 + m] = (__half)acc[ct][reg];
        }
    }
}

// ---------------------------------------------------------------------------
// 2) aggregation + self-loop + gcn bias + BN + ReLU.  Wave-per-node.
//    UNSCALED table; per-edge weight dinv[r] = rsqrt(cnt[r]+1), cnt gather
//    issued alongside the row gather.  2-deep software pipeline.
//    OUTF16: write h as fp16 (feeds gemm1h) vs f32 (feeds pool_head).
template<bool OUTF16>
__global__ __launch_bounds__(256) void agg_bn_kernel(
        const __half* __restrict__ xwh, const int* __restrict__ cnt,
        const unsigned short* __restrict__ ssrc, int cap,
        const float* __restrict__ b, const float* __restrict__ g,
        const float* __restrict__ bb, const float* __restrict__ m,
        const float* __restrict__ var,
        void* __restrict__ out, int N) {
    int wave = (blockIdx.x * blockDim.x + threadIdx.x) >> 6;
    int lane = threadIdx.x & 63;
    if (wave >= N) return;
    int c   = wave;
    int sub = lane >> 3;        // which of 8 concurrent edges
    int f2  = lane & 7;         // feature group: feats 8*f2 .. 8*f2+7
    const uint4* xw8 = (const uint4*)xwh;
    int n = cnt[c];
    if (n > cap) n = cap;
    float dc = rsqrtf((float)n + 1.0f);
    size_t sbase = (size_t)c * cap;
    // one coalesced load of the whole slot list (slot = lane)
    int idx = (lane < cap) ? (int)ssrc[sbase + lane] : 0;
    // self-loop gather issued early (sub==0 lanes cover all 8 chunks)
    uint4 vself = make_uint4(0u, 0u, 0u, 0u);
    if (sub == 0) vself = xw8[(size_t)c * 8 + f2];
    int t = (n + 7) >> 3;
    float4 accA = make_float4(0.f, 0.f, 0.f, 0.f);
    float4 accB = accA;

    uint4 v0 = make_uint4(0u,0u,0u,0u), v1 = v0;
    int   cv0 = -1, cv1 = -1;
    auto issue = [&](int k, uint4& v, int& cv) {
        int s = k * 8 + sub;
        int sc = (s < n) ? s : 0;            // shfl executed by ALL lanes
        int r  = __shfl(idx, sc, 64);
        if (s >= n) r = c;                   // redirect invalid to cache-hot row
        cv = (s < n) ? cnt[r] : -1;          // cnt gather ∥ row gather
        v  = xw8[(size_t)r * 8 + f2];
    };
    auto consume = [&](const uint4& v, int cv) {
        if (cv >= 0) acc16(v, rsqrtf((float)cv + 1.0f), accA, accB);
    };
    if (t > 0) issue(0, v0, cv0);
    if (t > 1) issue(1, v1, cv1);
    for (int k = 0; k < t; k++) {
        consume(v0, cv0);
        v0 = v1; cv0 = cv1;
        if (k + 2 < t) issue(k + 2, v1, cv1); else cv1 = -1;
    }
    if (sub == 0) acc16(vself, dc, accA, accB);   // self term
#pragma unroll
    for (int off = 8; off < 64; off <<= 1) {
        accA.x += __shfl_xor(accA.x, off, 64); accA.y += __shfl_xor(accA.y, off, 64);
        accA.z += __shfl_xor(accA.z, off, 64); accA.w += __shfl_xor(accA.w, off, 64);
        accB.x += __shfl_xor(accB.x, off, 64); accB.y += __shfl_xor(accB.y, off, 64);
        accB.z += __shfl_xor(accB.z, off, 64); accB.w += __shfl_xor(accB.w, off, 64);
    }
    if (sub < 2) {   // BN+ReLU epilogue split across 2 subs
        int i4 = 2 * f2 + sub;
        float4 acc = sub ? accB : accA;
        float4 b4  = ((const float4*)b)[i4];
        float4 m4  = ((const float4*)m)[i4];
        float4 v4_ = ((const float4*)var)[i4];
        float4 g4  = ((const float4*)g)[i4];
        float4 bb4 = ((const float4*)bb)[i4];
        float4 h;
        h.x = (acc.x * dc + b4.x - m4.x) * (1.0f / sqrtf(v4_.x + EPS)) * g4.x + bb4.x;
        h.y = (acc.y * dc + b4.y - m4.y) * (1.0f / sqrtf(v4_.y + EPS)) * g4.y + bb4.y;
        h.z = (acc.z * dc + b4.z - m4.z) * (1.0f / sqrtf(v4_.z + EPS)) * g4.z + bb4.z;
        h.w = (acc.w * dc + b4.w - m4.w) * (1.0f / sqrtf(v4_.w + EPS)) * g4.w + bb4.w;
        h.x = h.x > 0.f ? h.x : 0.f;
        h.y = h.y > 0.f ? h.y : 0.f;
        h.z = h.z > 0.f ? h.z : 0.f;
        h.w = h.w > 0.f ? h.w : 0.f;
        if (OUTF16) {
            half4_t hv = {(_Float16)h.x, (_Float16)h.y, (_Float16)h.z, (_Float16)h.w};
            *(half4_t*)((__half*)out + (size_t)c * 64 + i4 * 4) = hv;
        } else {
            ((float4*)out)[(size_t)c * 16 + i4] = h;
        }
    }
}

// ---------------------------------------------------------------------------
// 3) MFMA GEMM, fp16 input: Yh[N,64] = Xh[N,64] @ W[64,64]  (plain, unscaled)
__global__ __launch_bounds__(256) void gemm64h_kernel(const __half* __restrict__ Xh,
                                                      const float* __restrict__ W,
                                                      __half* __restrict__ Yh, int N) {
    __shared__ _Float16 Xs[64 * WP];   // [row][k]
    __shared__ _Float16 Wt[64 * WP];   // [n][k]
    int tid  = threadIdx.x;
    int base = blockIdx.x * 64;
    for (int i = tid; i < 4096; i += 256) {
        int k = i >> 6, n = i & 63;
        Wt[n * WP + k] = (_Float16)W[i];
    }
    for (int i = tid; i < 512; i += 256) {   // 64 rows x 8 16B-chunks
        int r = i >> 3, c8 = (i & 7) * 8;
        uint4 v = (base + r < N)
            ? ((const uint4*)Xh)[(size_t)(base + r) * 8 + (i & 7)]
            : make_uint4(0u, 0u, 0u, 0u);
        *(uint4*)&Xs[r * WP + c8] = v;
    }
    __syncthreads();
    int wave  = tid >> 6;
    int lane  = tid & 63;
    int m     = lane & 15;
    int q     = lane >> 4;
    int row16 = wave * 16;
    half8_t a0 = *(const half8_t*)&Xs[(row16 + m) * WP + q * 8];
    half8_t a1 = *(const half8_t*)&Xs[(row16 + m) * WP + 32 + q * 8];
    f32x4 acc[4];
#pragma unroll
    for (int ct = 0; ct < 4; ct++) {
        half8_t b0 = *(const half8_t*)&Wt[(ct * 16 + m) * WP + q * 8];
        half8_t b1 = *(const half8_t*)&Wt[(ct * 16 + m) * WP + 32 + q * 8];
        f32x4 c = {0.f, 0.f, 0.f, 0.f};
        c = __builtin_amdgcn_mfma_f32_16x16x32_f16(a0, b0, c, 0, 0, 0);
        c = __builtin_amdgcn_mfma_f32_16x16x32_f16(a1, b1, c, 0, 0, 0);
        acc[ct] = c;
    }
#pragma unroll
    for (int ct = 0; ct < 4; ct++) {
#pragma unroll
        for (int reg = 0; reg < 4; reg++) {
            int row = base + row16 + q * 4 + reg;
            if (row < N)
                Yh[(size_t)row * 64 + ct * 16 + m] = (__half)acc[ct][reg];
        }
    }
}

// ---------------------------------------------------------------------------
// 4) fused mean-pool (via sorted-batch binary search) + full MLP head.
__global__ __launch_bounds__(256) void pool_head_kernel(
        const float* __restrict__ h, const int* __restrict__ batch,
        const float* __restrict__ hW1, const float* __restrict__ hb1,
        const float* __restrict__ hg1, const float* __restrict__ hbb1,
        const float* __restrict__ hm1, const float* __restrict__ hv1,
        const float* __restrict__ hW2, const float* __restrict__ hb2,
        const float* __restrict__ hg2, const float* __restrict__ hbb2,
        const float* __restrict__ hm2, const float* __restrict__ hv2,
        const float* __restrict__ hW3, const float* __restrict__ hb3,
        const float* __restrict__ hW4, const float* __restrict__ hb4,
        float* __restrict__ out) {
    __shared__ int se[2];
    __shared__ float red[256];
    __shared__ float pooled[64];
    __shared__ float z1[256];
    __shared__ float z2[128];
    __shared__ float z3[64];
    int g = blockIdx.x;
    int t = threadIdx.x;
    if (t < 2) {
        int target = g + t;
        int lo = 0, hi = N_NODES;
        while (lo < hi) {
            int mid = (lo + hi) >> 1;
            if (batch[mid] < target) lo = mid + 1; else hi = mid;
        }
        se[t] = lo;
    }
    __syncthreads();
    int start = se[0], end = se[1];
    {   // mean pool: 4 row-groups x 64 features
        int f = t & 63, rg = t >> 6;
        float part = 0.0f;
        for (int r = start + rg; r < end; r += 4) part += h[(size_t)r * 64 + f];
        red[t] = part;
        __syncthreads();
        if (t < 64) {
            float s = red[t] + red[t + 64] + red[t + 128] + red[t + 192];
            float cnt = (float)(end - start);
            cnt = cnt > 1.0f ? cnt : 1.0f;
            pooled[t] = s / cnt;
        }
    }
    __syncthreads();
    {   // layer 1: 64 -> 256, BN + relu
        float acc = hb1[t];
#pragma unroll
        for (int k = 0; k < 64; k++) acc += pooled[k] * hW1[k * 256 + t];
        acc = (acc - hm1[t]) * (1.0f / sqrtf(hv1[t] + EPS)) * hg1[t] + hbb1[t];
        z1[t] = acc > 0.0f ? acc : 0.0f;
    }
    __syncthreads();
    if (t < 128) {  // layer 2: 256 -> 128, BN + relu
        float acc = hb2[t];
#pragma unroll 8
        for (int k = 0; k < 256; k++) acc += z1[k] * hW2[k * 128 + t];
        acc = (acc - hm2[t]) * (1.0f / sqrtf(hv2[t] + EPS)) * hg2[t] + hbb2[t];
        z2[t] = acc > 0.0f ? acc : 0.0f;
    }
    __syncthreads();
    if (t < 64) {   // layer 3: 128 -> 64, relu
        float acc = hb3[t];
#pragma unroll 8
        for (int k = 0; k < 128; k++) acc += z2[k] * hW3[k * 64 + t];
        z3[t] = acc > 0.0f ? acc : 0.0f;
    }
    __syncthreads();
    if (t < 64) {   // layer 4: 64 -> 1, wave reduce
        float v = z3[t] * hW4[t];
        for (int off = 32; off > 0; off >>= 1) v += __shfl_down(v, off, 64);
        if (t == 0) out[g] = v + hb4[0];
    }
}

extern "C" void kernel_launch(void* const* d_in, const int* in_sizes, int n_in,
                              void* d_out, int out_size, void* d_ws, size_t ws_size,
                              hipStream_t stream) {
    const float* x     = (const float*)d_in[0];
    const int*   ei    = (const int*)d_in[1];   // [2, E] int32
    const int*   batch = (const int*)d_in[2];
    const float* W0 = (const float*)d_in[3];
    const float* b0 = (const float*)d_in[4];
    const float* g0 = (const float*)d_in[5];
    const float* bb0 = (const float*)d_in[6];
    const float* m0 = (const float*)d_in[7];
    const float* v0 = (const float*)d_in[8];
    const float* W1 = (const float*)d_in[9];
    const float* b1 = (const float*)d_in[10];
    const float* g1 = (const float*)d_in[11];
    const float* bb1 = (const float*)d_in[12];
    const float* m1 = (const float*)d_in[13];
    const float* v1 = (const float*)d_in[14];
    const float* hW1 = (const float*)d_in[15];
    const float* hb1 = (const float*)d_in[16];
    const float* hg1 = (const float*)d_in[17];
    const float* hbb1 = (const float*)d_in[18];
    const float* hm1 = (const float*)d_in[19];
    const float* hv1 = (const float*)d_in[20];
    const float* hW2 = (const float*)d_in[21];
    const float* hb2 = (const float*)d_in[22];
    const float* hg2 = (const float*)d_in[23];
    const float* hbb2 = (const float*)d_in[24];
    const float* hm2 = (const float*)d_in[25];
    const float* hv2 = (const float*)d_in[26];
    const float* hW3 = (const float*)d_in[27];
    const float* hb3 = (const float*)d_in[28];
    const float* hW4 = (const float*)d_in[29];
    const float* hb4 = (const float*)d_in[30];
    float* out = (float*)d_out;

    // workspace layout (16B-aligned pieces)
    __half* xwhA = (__half*)d_ws;                            // N*64 fp16 (table0 / table1)
    __half* xwhB = xwhA + (size_t)N_NODES * D;               // N*64 fp16 (h0)
    float*  bufB = (float*)(xwhB + (size_t)N_NODES * D);     // N*64 f32 (h1 for head)
    int*    cnt  = (int*)(bufB + (size_t)N_NODES * D);       // N ints (in-degree)
    unsigned short* ssrc = (unsigned short*)(cnt + N_NODES); // N*cap ushorts

    size_t used = (size_t)2 * N_NODES * D * 2 + (size_t)N_NODES * D * 4
                + (size_t)N_NODES * 4;
    int cap = 64;
    if (ws_size >= used) {
        size_t avail = (ws_size - used) / ((size_t)N_NODES * 2);
        if (avail < (size_t)cap) cap = (int)avail & ~7;
    } else {
        cap = 0;
    }

    const int NT = 256;
    (void)hipMemsetAsync(cnt, 0, (size_t)N_NODES * 4, stream);

    // 1) gemm0 ∥ partitioned CSR build (LDS-compacted flush)
    build_gemm_kernel<<<SCAT_GRID + GEMM_BLOCKS, NT, 0, stream>>>(
        ei, cnt, ssrc, cap, x, W0, xwhA);

    // 2) agg0 + BN + ReLU -> h0 (fp16)
    agg_bn_kernel<true><<<(N_NODES * 64) / NT, NT, 0, stream>>>(
        xwhA, cnt, ssrc, cap, b0, g0, bb0, m0, v0, xwhB, N_NODES);

    // 3) gemm1 (fp16 in, fp16 out, unscaled) -> table1
    gemm64h_kernel<<<GEMM_BLOCKS, NT, 0, stream>>>(xwhB, W1, xwhA, N_NODES);

    // 4) agg1 + BN + ReLU -> h1 (f32)
    agg_bn_kernel<false><<<(N_NODES * 64) / NT, NT, 0, stream>>>(
        xwhA, cnt, ssrc, cap, b1, g1, bb1, m1, v1, bufB, N_NODES);

    // 5) mean pool + MLP head (fused)
    pool_head_kernel<<<NUM_GRAPHS, NT, 0, stream>>>(bufB, batch,
        hW1, hb1, hg1, hbb1, hm1, hv1,
        hW2, hb2, hg2, hbb2, hm2, hv2,
        hW3, hb3, hW4, hb4, out);
}

// Round 12
// 260.481 us; speedup vs baseline: 3.5063x; 1.0189x over previous
//
#include <hip/hip_runtime.h>
#include <hip/hip_bf16.h>
#include <hip/hip_fp16.h>

#define N_NODES 50000
#define N_EDGES 800000
#define NUM_GRAPHS 256
#define D 64
#define EPS 1e-5f
#define N_PART 8
#define PART_SIZE (N_NODES / N_PART)   // 6250
#define SCAT_CHUNKS 512
#define SCAT_GRID (SCAT_CHUNKS * N_PART)
#define GEMM_BLOCKS ((N_NODES + 63) / 64)   // 782
#define WP 72   // padded LDS row stride in halves (16B-aligned, conflict-breaking)

typedef _Float16 half8_t __attribute__((ext_vector_type(8)));
typedef _Float16 half4_t __attribute__((ext_vector_type(4)));
typedef float f32x4 __attribute__((ext_vector_type(4)));

// ---------------------------------------------------------------------------
// accumulate a 16B (8-half) chunk with weight w into two float4 accumulators
__device__ __forceinline__ void acc16(const uint4& v, float w, float4& A, float4& B) {
    const __half2* hp = (const __half2*)&v;
    float2 q0 = __half22float2(hp[0]), q1 = __half22float2(hp[1]);
    float2 q2 = __half22float2(hp[2]), q3 = __half22float2(hp[3]);
    A.x += w * q0.x; A.y += w * q0.y; A.z += w * q1.x; A.w += w * q1.y;
    B.x += w * q2.x; B.y += w * q2.y; B.z += w * q3.x; B.w += w * q3.y;
}

// ---------------------------------------------------------------------------
// 1) FUSED: gemm0 (blocks 0..781) ∥ XCD-partitioned slotted-CSR build
//    (blocks 782..).  Partitioning keeps each dst-range's cnt/ssrc lines on
//    ONE XCD's L2 -> single writeback per ssrc cacheline.  X loads are NT
//    (read-once); table stores are PLAIN (tables must stay cache-resident
//    for the agg gathers — NT stores cost 3x on agg, round-8 lesson).
//    Table is UNSCALED fp16 — dinv applied per-edge in agg (no cnt dep).
__global__ __launch_bounds__(256) void build_gemm_kernel(
        const int* __restrict__ ei, int* __restrict__ cnt,
        unsigned short* __restrict__ ssrc, int cap,
        const float* __restrict__ X, const float* __restrict__ W,
        __half* __restrict__ Yh) {
    __shared__ _Float16 Xs[64 * WP];   // [row][k]
    __shared__ _Float16 Wt[64 * WP];   // [n][k]
    if (blockIdx.x >= GEMM_BLOCKS) {
        // ---- scatter part (blockIdx&7 -> XCD affinity on dst partition) ----
        int scat  = blockIdx.x - GEMM_BLOCKS;
        int p     = blockIdx.x & (N_PART - 1);
        int chunk = scat >> 3;
        const int per = (((N_EDGES + SCAT_CHUNKS - 1) / SCAT_CHUNKS) + 3) & ~3;  // 1564
        int lo = chunk * per;
        int hi = lo + per; if (hi > N_EDGES) hi = N_EDGES;
        for (int e4 = lo + (int)threadIdx.x * 4; e4 < hi; e4 += 1024) {
            int4 c4 = *(const int4*)&ei[N_EDGES + e4];   // 16B-aligned: lo%4==0
            const int* cc = (const int*)&c4;
#pragma unroll
            for (int k = 0; k < 4; k++) {
                int e = e4 + k;
                if (e < hi) {
                    int c = cc[k];
                    if (c / PART_SIZE == p) {
                        int r = ei[e];
                        int pos = atomicAdd(&cnt[c], 1);
                        if (pos < cap) ssrc[(size_t)c * cap + pos] = (unsigned short)r;
                    }
                }
            }
        }
        return;
    }
    // ---- gemm0 part ----
    int tid  = threadIdx.x;
    int base = blockIdx.x * 64;
    for (int i = tid; i < 4096; i += 256) {       // stage W^T fp16
        int k = i >> 6, n = i & 63;
        Wt[n * WP + k] = (_Float16)W[i];
    }
    for (int i = tid; i < 1024; i += 256) {       // stage X rows fp16 (NT loads)
        int r = i >> 4, c4 = (i & 15) * 4;
        f32x4 xv;
        if (base + r < N_NODES) {
            xv = __builtin_nontemporal_load(
                     &((const f32x4*)X)[(size_t)(base + r) * 16 + (i & 15)]);
        } else {
            xv = (f32x4){0.f, 0.f, 0.f, 0.f};
        }
        _Float16* dst = &Xs[r * WP + c4];
        dst[0] = (_Float16)xv.x; dst[1] = (_Float16)xv.y;
        dst[2] = (_Float16)xv.z; dst[3] = (_Float16)xv.w;
    }
    __syncthreads();
    int wave  = tid >> 6;
    int lane  = tid & 63;
    int m     = lane & 15;
    int q     = lane >> 4;
    int row16 = wave * 16;
    half8_t a0 = *(const half8_t*)&Xs[(row16 + m) * WP + q * 8];
    half8_t a1 = *(const half8_t*)&Xs[(row16 + m) * WP + 32 + q * 8];
    f32x4 acc[4];
#pragma unroll
    for (int ct = 0; ct < 4; ct++) {
        half8_t b0 = *(const half8_t*)&Wt[(ct * 16 + m) * WP + q * 8];
        half8_t b1 = *(const half8_t*)&Wt[(ct * 16 + m) * WP + 32 + q * 8];
        f32x4 c = {0.f, 0.f, 0.f, 0.f};
        c = __builtin_amdgcn_mfma_f32_16x16x32_f16(a0, b0, c, 0, 0, 0);
        c = __builtin_amdgcn_mfma_f32_16x16x32_f16(a1, b1, c, 0, 0, 0);
        acc[ct] = c;
    }
#pragma unroll
    for (int ct = 0; ct < 4; ct++) {
#pragma unroll
        for (int reg = 0; reg < 4; reg++) {
            int row = base + row16 + q * 4 + reg;
            if (row < N_NODES)
                Yh[(size_t)row * 64 + ct * 16 + m] = (__half)acc[ct][reg];
        }
    }
}

// ---------------------------------------------------------------------------
// 2) aggregation + self-loop + gcn bias + BN + ReLU.  Wave-per-node.
//    Table is UNSCALED; per-edge weight dinv[r] = rsqrt(cnt[r]+1) with the
//    cnt gather issued alongside the row gather (independent loads).
//    2-deep software pipeline: two row-gathers + two cnt loads in flight.
//    OUTF16: write h as fp16 (consumed by gemm1h) vs f32 (consumed by head).
template<bool OUTF16>
__global__ __launch_bounds__(256) void agg_bn_kernel(
        const __half* __restrict__ xwh, const int* __restrict__ cnt,
        const unsigned short* __restrict__ ssrc, int cap,
        const float* __restrict__ b, const float* __restrict__ g,
        const float* __restrict__ bb, const float* __restrict__ m,
        const float* __restrict__ var,
        void* __restrict__ out, int N) {
    int wave = (blockIdx.x * blockDim.x + threadIdx.x) >> 6;
    int lane = threadIdx.x & 63;
    if (wave >= N) return;
    int c   = wave;
    int sub = lane >> 3;        // which of 8 concurrent edges
    int f2  = lane & 7;         // feature group: feats 8*f2 .. 8*f2+7
    const uint4* xw8 = (const uint4*)xwh;
    int n = cnt[c];
    if (n > cap) n = cap;
    float dc = rsqrtf((float)n + 1.0f);
    size_t sbase = (size_t)c * cap;
    // one coalesced load of the whole slot list (slot = lane)
    int idx = (lane < cap) ? (int)ssrc[sbase + lane] : 0;
    // self-loop gather issued early (sub==0 lanes cover all 8 chunks)
    uint4 vself = make_uint4(0u, 0u, 0u, 0u);
    if (sub == 0) vself = xw8[(size_t)c * 8 + f2];
    int t = (n + 7) >> 3;
    float4 accA = make_float4(0.f, 0.f, 0.f, 0.f);
    float4 accB = accA;

    uint4 v0 = make_uint4(0u,0u,0u,0u), v1 = v0;
    int   cv0 = -1, cv1 = -1;
    auto issue = [&](int k, uint4& v, int& cv) {
        int s = k * 8 + sub;
        int sc = (s < n) ? s : 0;            // shfl executed by ALL lanes
        int r  = __shfl(idx, sc, 64);
        if (s >= n) r = c;                   // redirect invalid to cache-hot row
        cv = (s < n) ? cnt[r] : -1;          // cnt gather ∥ row gather
        v  = xw8[(size_t)r * 8 + f2];
    };
    auto consume = [&](const uint4& v, int cv) {
        if (cv >= 0) acc16(v, rsqrtf((float)cv + 1.0f), accA, accB);
    };
    if (t > 0) issue(0, v0, cv0);
    if (t > 1) issue(1, v1, cv1);
    for (int k = 0; k < t; k++) {
        consume(v0, cv0);
        v0 = v1; cv0 = cv1;
        if (k + 2 < t) issue(k + 2, v1, cv1); else cv1 = -1;
    }
    if (sub == 0) acc16(vself, dc, accA, accB);   // self term: dc (epilogue adds 2nd dc)
#pragma unroll
    for (int off = 8; off < 64; off <<= 1) {
        accA.x += __shfl_xor(accA.x, off, 64); accA.y += __shfl_xor(accA.y, off, 64);
        accA.z += __shfl_xor(accA.z, off, 64); accA.w += __shfl_xor(accA.w, off, 64);
        accB.x += __shfl_xor(accB.x, off, 64); accB.y += __shfl_xor(accB.y, off, 64);
        accB.z += __shfl_xor(accB.z, off, 64); accB.w += __shfl_xor(accB.w, off, 64);
    }
    if (sub < 2) {   // BN+ReLU epilogue split across 2 subs
        int i4 = 2 * f2 + sub;
        float4 acc = sub ? accB : accA;
        float4 b4  = ((const float4*)b)[i4];
        float4 m4  = ((const float4*)m)[i4];
        float4 v4_ = ((const float4*)var)[i4];
        float4 g4  = ((const float4*)g)[i4];
        float4 bb4 = ((const float4*)bb)[i4];
        float4 h;
        h.x = (acc.x * dc + b4.x - m4.x) * (1.0f / sqrtf(v4_.x + EPS)) * g4.x + bb4.x;
        h.y = (acc.y * dc + b4.y - m4.y) * (1.0f / sqrtf(v4_.y + EPS)) * g4.y + bb4.y;
        h.z = (acc.z * dc + b4.z - m4.z) * (1.0f / sqrtf(v4_.z + EPS)) * g4.z + bb4.z;
        h.w = (acc.w * dc + b4.w - m4.w) * (1.0f / sqrtf(v4_.w + EPS)) * g4.w + bb4.w;
        h.x = h.x > 0.f ? h.x : 0.f;
        h.y = h.y > 0.f ? h.y : 0.f;
        h.z = h.z > 0.f ? h.z : 0.f;
        h.w = h.w > 0.f ? h.w : 0.f;
        if (OUTF16) {
            half4_t hv = {(_Float16)h.x, (_Float16)h.y, (_Float16)h.z, (_Float16)h.w};
            *(half4_t*)((__half*)out + (size_t)c * 64 + i4 * 4) = hv;
        } else {
            ((float4*)out)[(size_t)c * 16 + i4] = h;
        }
    }
}

// ---------------------------------------------------------------------------
// 3) MFMA GEMM, fp16 input: Yh[N,64] = Xh[N,64] @ W[64,64]  (plain, unscaled)
__global__ __launch_bounds__(256) void gemm64h_kernel(const __half* __restrict__ Xh,
                                                      const float* __restrict__ W,
                                                      __half* __restrict__ Yh, int N) {
    __shared__ _Float16 Xs[64 * WP];   // [row][k]
    __shared__ _Float16 Wt[64 * WP];   // [n][k]
    int tid  = threadIdx.x;
    int base = blockIdx.x * 64;
    for (int i = tid; i < 4096; i += 256) {
        int k = i >> 6, n = i & 63;
        Wt[n * WP + k] = (_Float16)W[i];
    }
    for (int i = tid; i < 512; i += 256) {   // 64 rows x 8 16B-chunks
        int r = i >> 3, c8 = (i & 7) * 8;
        uint4 v = (base + r < N)
            ? ((const uint4*)Xh)[(size_t)(base + r) * 8 + (i & 7)]
            : make_uint4(0u, 0u, 0u, 0u);
        *(uint4*)&Xs[r * WP + c8] = v;
    }
    __syncthreads();
    int wave  = tid >> 6;
    int lane  = tid & 63;
    int m     = lane & 15;
    int q     = lane >> 4;
    int row16 = wave * 16;
    half8_t a0 = *(const half8_t*)&Xs[(row16 + m) * WP + q * 8];
    half8_t a1 = *(const half8_t*)&Xs[(row16 + m) * WP + 32 + q * 8];
    f32x4 acc[4];
#pragma unroll
    for (int ct = 0; ct < 4; ct++) {
        half8_t b0 = *(const half8_t*)&Wt[(ct * 16 + m) * WP + q * 8];
        half8_t b1 = *(const half8_t*)&Wt[(ct * 16 + m) * WP + 32 + q * 8];
        f32x4 c = {0.f, 0.f, 0.f, 0.f};
        c = __builtin_amdgcn_mfma_f32_16x16x32_f16(a0, b0, c, 0, 0, 0);
        c = __builtin_amdgcn_mfma_f32_16x16x32_f16(a1, b1, c, 0, 0, 0);
        acc[ct] = c;
    }
#pragma unroll
    for (int ct = 0; ct < 4; ct++) {
#pragma unroll
        for (int reg = 0; reg < 4; reg++) {
            int row = base + row16 + q * 4 + reg;
            if (row < N)
                Yh[(size_t)row * 64 + ct * 16 + m] = (__half)acc[ct][reg];
        }
    }
}

// ---------------------------------------------------------------------------
// 4) fused mean-pool (via sorted-batch binary search) + full MLP head.
__global__ __launch_bounds__(256) void pool_head_kernel(
        const float* __restrict__ h, const int* __restrict__ batch,
        const float* __restrict__ hW1, const float* __restrict__ hb1,
        const float* __restrict__ hg1, const float* __restrict__ hbb1,
        const float* __restrict__ hm1, const float* __restrict__ hv1,
        const float* __restrict__ hW2, const float* __restrict__ hb2,
        const float* __restrict__ hg2, const float* __restrict__ hbb2,
        const float* __restrict__ hm2, const float* __restrict__ hv2,
        const float* __restrict__ hW3, const float* __restrict__ hb3,
        const float* __restrict__ hW4, const float* __restrict__ hb4,
        float* __restrict__ out) {
    __shared__ int se[2];
    __shared__ float red[256];
    __shared__ float pooled[64];
    __shared__ float z1[256];
    __shared__ float z2[128];
    __shared__ float z3[64];
    int g = blockIdx.x;
    int t = threadIdx.x;
    if (t < 2) {
        int target = g + t;
        int lo = 0, hi = N_NODES;
        while (lo < hi) {
            int mid = (lo + hi) >> 1;
            if (batch[mid] < target) lo = mid + 1; else hi = mid;
        }
        se[t] = lo;
    }
    __syncthreads();
    int start = se[0], end = se[1];
    {   // mean pool: 4 row-groups x 64 features
        int f = t & 63, rg = t >> 6;
        float part = 0.0f;
        for (int r = start + rg; r < end; r += 4) part += h[(size_t)r * 64 + f];
        red[t] = part;
        __syncthreads();
        if (t < 64) {
            float s = red[t] + red[t + 64] + red[t + 128] + red[t + 192];
            float cnt = (float)(end - start);
            cnt = cnt > 1.0f ? cnt : 1.0f;
            pooled[t] = s / cnt;
        }
    }
    __syncthreads();
    {   // layer 1: 64 -> 256, BN + relu
        float acc = hb1[t];
#pragma unroll
        for (int k = 0; k < 64; k++) acc += pooled[k] * hW1[k * 256 + t];
        acc = (acc - hm1[t]) * (1.0f / sqrtf(hv1[t] + EPS)) * hg1[t] + hbb1[t];
        z1[t] = acc > 0.0f ? acc : 0.0f;
    }
    __syncthreads();
    if (t < 128) {  // layer 2: 256 -> 128, BN + relu
        float acc = hb2[t];
#pragma unroll 8
        for (int k = 0; k < 256; k++) acc += z1[k] * hW2[k * 128 + t];
        acc = (acc - hm2[t]) * (1.0f / sqrtf(hv2[t] + EPS)) * hg2[t] + hbb2[t];
        z2[t] = acc > 0.0f ? acc : 0.0f;
    }
    __syncthreads();
    if (t < 64) {   // layer 3: 128 -> 64, relu
        float acc = hb3[t];
#pragma unroll 8
        for (int k = 0; k < 128; k++) acc += z2[k] * hW3[k * 64 + t];
        z3[t] = acc > 0.0f ? acc : 0.0f;
    }
    __syncthreads();
    if (t < 64) {   // layer 4: 64 -> 1, wave reduce
        float v = z3[t] * hW4[t];
        for (int off = 32; off > 0; off >>= 1) v += __shfl_down(v, off, 64);
        if (t == 0) out[g] = v + hb4[0];
    }
}

extern "C" void kernel_launch(void* const* d_in, const int* in_sizes, int n_in,
                              void* d_out, int out_size, void* d_ws, size_t ws_size,
                              hipStream_t stream) {
    const float* x     = (const float*)d_in[0];
    const int*   ei    = (const int*)d_in[1];   // [2, E] int32
    const int*   batch = (const int*)d_in[2];
    const float* W0 = (const float*)d_in[3];
    const float* b0 = (const float*)d_in[4];
    const float* g0 = (const float*)d_in[5];
    const float* bb0 = (const float*)d_in[6];
    const float* m0 = (const float*)d_in[7];
    const float* v0 = (const float*)d_in[8];
    const float* W1 = (const float*)d_in[9];
    const float* b1 = (const float*)d_in[10];
    const float* g1 = (const float*)d_in[11];
    const float* bb1 = (const float*)d_in[12];
    const float* m1 = (const float*)d_in[13];
    const float* v1 = (const float*)d_in[14];
    const float* hW1 = (const float*)d_in[15];
    const float* hb1 = (const float*)d_in[16];
    const float* hg1 = (const float*)d_in[17];
    const float* hbb1 = (const float*)d_in[18];
    const float* hm1 = (const float*)d_in[19];
    const float* hv1 = (const float*)d_in[20];
    const float* hW2 = (const float*)d_in[21];
    const float* hb2 = (const float*)d_in[22];
    const float* hg2 = (const float*)d_in[23];
    const float* hbb2 = (const float*)d_in[24];
    const float* hm2 = (const float*)d_in[25];
    const float* hv2 = (const float*)d_in[26];
    const float* hW3 = (const float*)d_in[27];
    const float* hb3 = (const float*)d_in[28];
    const float* hW4 = (const float*)d_in[29];
    const float* hb4 = (const float*)d_in[30];
    float* out = (float*)d_out;

    // workspace layout (16B-aligned pieces)
    __half* xwhA = (__half*)d_ws;                            // N*64 fp16 (table0 / table1)
    __half* xwhB = xwhA + (size_t)N_NODES * D;               // N*64 fp16 (h0)
    float*  bufB = (float*)(xwhB + (size_t)N_NODES * D);     // N*64 f32 (h1 for head)
    int*    cnt  = (int*)(bufB + (size_t)N_NODES * D);       // N ints (in-degree)
    unsigned short* ssrc = (unsigned short*)(cnt + N_NODES); // N*cap ushorts

    size_t used = (size_t)2 * N_NODES * D * 2 + (size_t)N_NODES * D * 4
                + (size_t)N_NODES * 4;
    int cap = 64;
    if (ws_size >= used) {
        size_t avail = (ws_size - used) / ((size_t)N_NODES * 2);
        if (avail < (size_t)cap) cap = (int)avail & ~7;
    } else {
        cap = 0;
    }

    const int NT = 256;
    (void)hipMemsetAsync(cnt, 0, (size_t)N_NODES * 4, stream);

    // 1) gemm0 ∥ partitioned CSR build (unscaled fp16 table — no cnt dep)
    build_gemm_kernel<<<SCAT_GRID + GEMM_BLOCKS, NT, 0, stream>>>(
        ei, cnt, ssrc, cap, x, W0, xwhA);

    // 2) agg0 + BN + ReLU -> h0 (fp16); unscaled table, per-edge cnt gather
    agg_bn_kernel<true><<<(N_NODES * 64) / NT, NT, 0, stream>>>(
        xwhA, cnt, ssrc, cap, b0, g0, bb0, m0, v0, xwhB, N_NODES);

    // 3) gemm1 (fp16 in, fp16 out, unscaled) -> table1
    gemm64h_kernel<<<GEMM_BLOCKS, NT, 0, stream>>>(xwhB, W1, xwhA, N_NODES);

    // 4) agg1 + BN + ReLU -> h1 (f32)
    agg_bn_kernel<false><<<(N_NODES * 64) / NT, NT, 0, stream>>>(
        xwhA, cnt, ssrc, cap, b1, g1, bb1, m1, v1, bufB, N_NODES);

    // 5) mean pool + MLP head (fused)
    pool_head_kernel<<<NUM_GRAPHS, NT, 0, stream>>>(bufB, batch,
        hW1, hb1, hg1, hbb1, hm1, hv1,
        hW2, hb2, hg2, hbb2, hm2, hv2,
        hW3, hb3, hW4, hb4, out);
}